// Round 2
// baseline (164.771 us; speedup 1.0000x reference)
//
#include <hip/hip_runtime.h>

// Fused grouped-QKV GEMM: out[t,kv,g,d] = sum_e in[t,e]*W[e,kv,g,d] + bias
// M=64, K=4096, N=6144. fp32 in/out.
//
// R9: reg-staged W pipeline (T14). R8's global_load_lds double-buffer was a
// null: the memory legalizer treats LDS-DMA conservatively and re-drains
// vmcnt(0) before the Ws ds_reads, defeating the counted vmcnt(4). Staging
// via global->VGPR->ds_write gives per-load counted waits instead: the
// ds_write of tile s+1 auto-waits ONLY its own 4 loads (issued one full tile
// earlier), while the depth-2 prefetch (WLOAD s+2, ALOAD s+1) stays in
// flight. One lgkmcnt(0)+s_barrier per tile; no vmcnt drain anywhere in the
// loop. LDS image identical to R8 (XOR-swizzled, 2-way banks on read), now
// swizzled at the ds_write address (legal only with reg-staging, m104).
// fp32 partials to d_ws + float4 reduce (no atomics).

#define N_COLS 6144
#define K_DIM  4096
#define Q_SZ   (64 * 4096)
#define K_OFF  Q_SZ
#define V_OFF  (Q_SZ + 64 * 1024)
#define OUT_ELEMS 393216   // 64*6144
#define NT     48          // n-tiles of 128
#define KSPLIT 16          // 256 k per block -> 768 blocks (3/CU)
#define BK     32
#define TILES  8           // 256/32

typedef __bf16 bf16x8 __attribute__((ext_vector_type(8)));
typedef float  f32x4  __attribute__((ext_vector_type(4)));

__device__ __forceinline__ int out_index(int t, int n) {
    const int kv = n / 768;
    const int g  = (n >> 7) % 6;
    const int d  = n & 127;
    if (g < 4)  return t * 4096 + kv * 512 + g * 128 + d;   // q
    if (g == 4) return K_OFF + t * 1024 + kv * 128 + d;     // k
    return V_OFF + t * 1024 + kv * 128 + d;                 // v
}

__global__ __launch_bounds__(256, 3)
void qkv_gemm(const float* __restrict__ in, const float* __restrict__ w,
              float* __restrict__ part) {
    __shared__ float Ws[2][BK * 128];   // 2 x 16KB fp32 W-tile, [k][n] k-major

    const int tid  = threadIdx.x;
    const int nt   = blockIdx.x % NT;    // adjacent blocks: adjacent n, same k
    const int kq   = blockIdx.x / NT;
    const int n0   = nt * 128;
    const int k0   = kq * (BK * TILES);
    const int wid  = tid >> 6;
    const int lane = tid & 63;
    const int l15  = lane & 15;
    const int kblk = lane >> 4;

    // W staging geometry: thread owns 4 16B chunks, r=0..3:
    //   global row k_r = r*8 + (tid>>5), cols 4c..4c+3 with c = tid&31.
    // LDS word [k*128 + (m ^ (((k>>3)&3)<<4))] holds W[k][m]; the ds_write
    // applies the XOR at chunk granularity: dest = k*128 + 4*(c ^ (r<<2)).
    // Read side (unchanged from R8): 2-way banks (free).
    const int t5 = tid >> 5;
    const int c  = tid & 31;

    f32x4 acc[2][4];
    #pragma unroll
    for (int a = 0; a < 2; ++a)
        #pragma unroll
        for (int b = 0; b < 4; ++b) acc[a][b] = (f32x4){0.f, 0.f, 0.f, 0.f};

    f32x4 wreg[2][4];          // 2 sets x 4 chunks (depth-2 W prefetch)
    float4 alo[4], ahi[4];     // single A set (reloaded right after pack)

    const float* wbase = w + (size_t)k0 * N_COLS + n0 + c * 4;

    auto WLOAD = [&](int s, int set) {
        const float* p = wbase + (size_t)s * BK * N_COLS;
        #pragma unroll
        for (int r = 0; r < 4; ++r)
            wreg[set][r] = *(const f32x4*)(p + (size_t)(r * 8 + t5) * N_COLS);
    };
    auto DSWRITE = [&](int set, int buf) {
        #pragma unroll
        for (int r = 0; r < 4; ++r)
            *(f32x4*)&Ws[buf][(r * 8 + t5) * 128 + 4 * (c ^ (r << 2))] =
                wreg[set][r];
    };
    auto ALOAD = [&](int s) {
        const int kc = k0 + s * BK;
        #pragma unroll
        for (int mi = 0; mi < 4; ++mi) {
            const float* ap = in + (size_t)(mi * 16 + l15) * K_DIM + kc + kblk * 8;
            alo[mi] = *(const float4*)ap;
            ahi[mi] = *(const float4*)(ap + 4);
        }
    };

    // prologue: tile0 -> buf0 (one exposed latency), tile1 loads in flight
    WLOAD(0, 0);
    ALOAD(0);
    WLOAD(1, 1);
    DSWRITE(0, 0);             // auto vmcnt wait: only wreg[0]'s 4 loads
    asm volatile("s_waitcnt lgkmcnt(0)" ::: "memory");
    __builtin_amdgcn_s_barrier();

    #pragma unroll
    for (int s = 0; s < TILES; ++s) {
        // 1. pack A(s): element j = k-offset j; (__bf16) cast = HW RNE cvt_pk
        bf16x8 av[4];
        #pragma unroll
        for (int mi = 0; mi < 4; ++mi) {
            av[mi][0] = (__bf16)alo[mi].x; av[mi][1] = (__bf16)alo[mi].y;
            av[mi][2] = (__bf16)alo[mi].z; av[mi][3] = (__bf16)alo[mi].w;
            av[mi][4] = (__bf16)ahi[mi].x; av[mi][5] = (__bf16)ahi[mi].y;
            av[mi][6] = (__bf16)ahi[mi].z; av[mi][7] = (__bf16)ahi[mi].w;
        }

        // 2. prefetch issues (stay in flight across the barrier below)
        if (s + 2 < TILES) WLOAD(s + 2, s & 1);
        if (s + 1 < TILES) ALOAD(s + 1);

        // 3. B-frags from Ws[s&1] + MFMA; wave wid owns n-frags {2wid, 2wid+1}
        #pragma unroll
        for (int nfi = 0; nfi < 2; ++nfi) {
            const int nb   = (wid * 2 + nfi) * 16 + l15;
            const int base = kblk * 1024 + (nb ^ (kblk << 4));
            bf16x8 bv;
            #pragma unroll
            for (int j = 0; j < 8; ++j)
                bv[j] = (__bf16)Ws[s & 1][base + j * 128];
            #pragma unroll
            for (int mi = 0; mi < 4; ++mi)
                acc[nfi][mi] = __builtin_amdgcn_mfma_f32_16x16x32_bf16(
                    av[mi], bv, acc[nfi][mi], 0, 0, 0);
        }

        // 4/5. commit tile s+1 into the other buffer; one barrier per tile
        if (s + 1 < TILES) {
            DSWRITE((s + 1) & 1, (s + 1) & 1);  // waits only WLOAD(s+1)
            asm volatile("s_waitcnt lgkmcnt(0)" ::: "memory");
            __builtin_amdgcn_s_barrier();
        }
    }

    // partials: C/D col = l15 (n), row = kblk*4 + r (token within m-frag)
    float* pb = part + (size_t)kq * OUT_ELEMS;
    #pragma unroll
    for (int nfi = 0; nfi < 2; ++nfi) {
        const int n = n0 + (wid * 2 + nfi) * 16 + l15;
        #pragma unroll
        for (int mi = 0; mi < 4; ++mi) {
            #pragma unroll
            for (int r = 0; r < 4; ++r) {
                const int t = mi * 16 + kblk * 4 + r;
                pb[(size_t)t * N_COLS + n] = acc[nfi][mi][r];
            }
        }
    }
}

// sum KSPLIT partials + bias, scatter to q|k|v. float4 lanes: d-chunks are
// 4-aligned and never cross a 128-d block, so out_index(t,n)..+3 contiguous.
__global__ __launch_bounds__(256)
void qkv_reduce(const float* __restrict__ part, const float* __restrict__ bias,
                float* __restrict__ out) {
    const int i = (blockIdx.x * 256 + threadIdx.x) << 2;   // 0..393212, 4-stride
    const int t = i / N_COLS;
    const int n = i - t * N_COLS;
    f32x4 s = *(const f32x4*)(bias + n);
    #pragma unroll
    for (int kq = 0; kq < KSPLIT; ++kq)
        s += *(const f32x4*)(part + (size_t)kq * OUT_ELEMS + i);
    *(f32x4*)(out + out_index(t, n)) = s;
}

extern "C" void kernel_launch(void* const* d_in, const int* in_sizes, int n_in,
                              void* d_out, int out_size, void* d_ws, size_t ws_size,
                              hipStream_t stream) {
    const float* in   = (const float*)d_in[0];  // [64, 4096]
    const float* w    = (const float*)d_in[1];  // [4096, 8, 6, 128]
    const float* bias = (const float*)d_in[2];  // [8, 6, 128]
    float* out  = (float*)d_out;
    float* part = (float*)d_ws;                 // 16 * 1.57MB = 25.2MB fp32

    qkv_gemm<<<NT * KSPLIT, 256, 0, stream>>>(in, w, part);
    qkv_reduce<<<OUT_ELEMS / 1024, 256, 0, stream>>>(part, bias, out);
}